// Round 3
// baseline (133.129 us; speedup 1.0000x reference)
//
#include <hip/hip_runtime.h>

// Problem constants (match reference): B=16, N=1024, D2H=1024, U=512
#define BB 16
#define NN 1024
#define DD 1024
#define UU 512

// Clang-native 16B vector (HIP's float4 is a class type -> rejected by
// __builtin_nontemporal_load/store; ext_vector_type is accepted).
typedef float vfloat4 __attribute__((ext_vector_type(4)));

// ---------------------------------------------------------------------------
// Kernel A: v_h[d] = sum_u W_h[u,d]*w_out[u]; v_m likewise;
//           C = (b_h+b_m)·w_out + b_out.
// 129 blocks: 0..63 -> W_h (4 d-chunks x 16 u-chunks), 64..127 -> W_m,
// 128 -> scalar C. Partials combined via atomicAdd into zeroed v_h/v_m.
// ---------------------------------------------------------------------------
__global__ __launch_bounds__(256) void prep_kernel(
    const float* __restrict__ W_h, const float* __restrict__ W_m,
    const float* __restrict__ b_h, const float* __restrict__ b_m,
    const float* __restrict__ w_out, const float* __restrict__ b_out,
    float* __restrict__ v_h, float* __restrict__ v_m, float* __restrict__ Cc) {
    int t = threadIdx.x;
    int blk = blockIdx.x;
    if (blk < 128) {
        const float* W = (blk < 64) ? W_h : W_m;
        float* v = (blk < 64) ? v_h : v_m;
        int b = blk & 63;
        int d = (b & 3) * 256 + t;      // 4 chunks of 256 d
        int u0 = (b >> 2) * 32;         // 16 chunks of 32 u
        float acc = 0.f;
        #pragma unroll
        for (int k = 0; k < 32; ++k) {
            // w_out[u0+k] is wave-uniform -> scalar load; W access coalesced in d
            acc += W[(size_t)(u0 + k) * DD + d] * w_out[u0 + k];
        }
        atomicAdd(v + d, acc);
    } else {
        __shared__ float red[256];
        float acc = 0.f;
        for (int u = t; u < UU; u += 256) acc += (b_h[u] + b_m[u]) * w_out[u];
        red[t] = acc;
        __syncthreads();
        for (int s = 128; s > 0; s >>= 1) {
            if (t < s) red[t] += red[t + s];
            __syncthreads();
        }
        if (t == 0) *Cc = red[0] + b_out[0];
    }
}

// ---------------------------------------------------------------------------
// Kernel B: sH[row] = x[row]·v_h + C ; sM[row] = x[row]·v_m   (row = b*N+n)
// One wave per row, 4 waves/block. v_h/v_m read straight from L2 (4 KB each,
// XCD-resident). x is streamed exactly once -> nontemporal loads keep it out
// of L2 so v_h/v_m/sH/sM stay hot.
// ---------------------------------------------------------------------------
__global__ __launch_bounds__(256) void row_dots_kernel(
    const float* __restrict__ x,
    const float* __restrict__ v_h, const float* __restrict__ v_m,
    const float* __restrict__ Cc,
    float* __restrict__ sH, float* __restrict__ sM) {
    int t = threadIdx.x;
    int wave = t >> 6, lane = t & 63;
    int row = blockIdx.x * 4 + wave;                 // [0, B*N)
    const vfloat4* xr = (const vfloat4*)(x + (size_t)row * DD);
    const float4* vh = (const float4*)v_h;
    const float4* vm = (const float4*)v_m;

    float ah = 0.f, am = 0.f;
    #pragma unroll
    for (int k = 0; k < 4; ++k) {
        int idx = lane + 64 * k;
        vfloat4 xv = __builtin_nontemporal_load(&xr[idx]);
        float4 hv = vh[idx];
        float4 mv = vm[idx];
        ah += xv.x * hv.x + xv.y * hv.y + xv.z * hv.z + xv.w * hv.w;
        am += xv.x * mv.x + xv.y * mv.y + xv.z * mv.z + xv.w * mv.w;
    }
    #pragma unroll
    for (int off = 32; off > 0; off >>= 1) {
        ah += __shfl_down(ah, off, 64);
        am += __shfl_down(am, off, 64);
    }
    if (lane == 0) {
        sH[row] = ah + *Cc;   // fold the scalar offset here
        sM[row] = am;
    }
}

// ---------------------------------------------------------------------------
// Kernel C: out[b,i,j] = sH[b*N+i] + sM[b*N+j]   (C already inside sH)
// One block per 8-row strip (8 rows always share a batch since 8 | N):
// the sM float4 is loaded ONCE per thread and reused for 8 stores, the 8
// sH scalars are block-uniform (SGPR loads). 8 independent nontemporal
// float4 stores per thread = deep store pipeline, 8x fewer blocks.
// ---------------------------------------------------------------------------
__global__ __launch_bounds__(256) void scores_kernel(
    const float* __restrict__ sH, const float* __restrict__ sM,
    vfloat4* __restrict__ out) {
    int bi0 = blockIdx.x * 8;                         // first row of strip
    int j4 = threadIdx.x;                             // float4 index in row
    const float4* mrow = (const float4*)(sM + (bi0 & ~(NN - 1)));
    float4 m = mrow[j4];
    float h[8];
    #pragma unroll
    for (int r = 0; r < 8; ++r) h[r] = sH[bi0 + r];   // block-uniform -> s_load
    #pragma unroll
    for (int r = 0; r < 8; ++r) {
        vfloat4 o;
        o.x = h[r] + m.x;
        o.y = h[r] + m.y;
        o.z = h[r] + m.z;
        o.w = h[r] + m.w;
        __builtin_nontemporal_store(o, &out[(size_t)(bi0 + r) * (NN / 4) + j4]);
    }
}

extern "C" void kernel_launch(void* const* d_in, const int* in_sizes, int n_in,
                              void* d_out, int out_size, void* d_ws, size_t ws_size,
                              hipStream_t stream) {
    const float* x     = (const float*)d_in[0];
    const float* W_h   = (const float*)d_in[1];
    const float* b_h   = (const float*)d_in[2];
    const float* W_m   = (const float*)d_in[3];
    const float* b_m   = (const float*)d_in[4];
    const float* w_out = (const float*)d_in[5];
    const float* b_out = (const float*)d_in[6];
    float* out = (float*)d_out;

    float* ws  = (float*)d_ws;
    float* v_h = ws;               // 1024
    float* v_m = ws + 1024;        // 1024
    float* Cc  = ws + 2048;        // 1
    float* sH  = ws + 4096;        // B*N = 16384
    float* sM  = ws + 4096 + 16384;

    // zero the atomicAdd targets (ws is poisoned 0xAA before every call)
    (void)hipMemsetAsync(ws, 0, 2048 * sizeof(float), stream);

    prep_kernel<<<129, 256, 0, stream>>>(W_h, W_m, b_h, b_m, w_out, b_out, v_h, v_m, Cc);
    row_dots_kernel<<<BB * NN / 4, 256, 0, stream>>>(x, v_h, v_m, Cc, sH, sM);
    scores_kernel<<<BB * NN / 8, 256, 0, stream>>>(sH, sM, (vfloat4*)out);
}

// Round 4
// 129.567 us; speedup vs baseline: 1.0275x; 1.0275x over previous
//
#include <hip/hip_runtime.h>

// Problem constants (match reference): B=16, N=1024, D2H=1024, U=512
#define BB 16
#define NN 1024
#define DD 1024
#define UU 512

// ---------------------------------------------------------------------------
// Kernel A: v_h[d] = sum_u W_h[u,d]*w_out[u]; v_m likewise;
//           C = (b_h+b_m)·w_out + b_out.
// 257 blocks: 0..127 -> W_h (4 d-chunks x 32 u-chunks), 128..255 -> W_m,
// 256 -> scalar C. Partials combined via atomicAdd into zeroed v_h/v_m.
// (u-chunks of 16: 2x the blocks of the old version -> latency-bound phase
//  now covers all 256 CUs instead of half.)
// ---------------------------------------------------------------------------
__global__ __launch_bounds__(256) void prep_kernel(
    const float* __restrict__ W_h, const float* __restrict__ W_m,
    const float* __restrict__ b_h, const float* __restrict__ b_m,
    const float* __restrict__ w_out, const float* __restrict__ b_out,
    float* __restrict__ v_h, float* __restrict__ v_m, float* __restrict__ Cc) {
    int t = threadIdx.x;
    int blk = blockIdx.x;
    if (blk < 256) {
        const float* W = (blk < 128) ? W_h : W_m;
        float* v = (blk < 128) ? v_h : v_m;
        int b = blk & 127;
        int d = (b & 3) * 256 + t;      // 4 chunks of 256 d
        int u0 = (b >> 2) * 16;         // 32 chunks of 16 u
        float acc = 0.f;
        #pragma unroll
        for (int k = 0; k < 16; ++k) {
            // w_out[u0+k] is wave-uniform -> scalar load; W access coalesced in d
            acc += W[(size_t)(u0 + k) * DD + d] * w_out[u0 + k];
        }
        atomicAdd(v + d, acc);
    } else {
        __shared__ float red[256];
        float acc = 0.f;
        for (int u = t; u < UU; u += 256) acc += (b_h[u] + b_m[u]) * w_out[u];
        red[t] = acc;
        __syncthreads();
        for (int s = 128; s > 0; s >>= 1) {
            if (t < s) red[t] += red[t + s];
            __syncthreads();
        }
        if (t == 0) *Cc = red[0] + b_out[0];
    }
}

// ---------------------------------------------------------------------------
// Kernel B: sH[row] = x[row]·v_h + C ; sM[row] = x[row]·v_m   (row = b*N+n)
// 16 rows per block: v_h/v_m staged in LDS ONCE per block (8 KB), then each
// of the 4 waves computes 4 rows. Cuts v cache traffic 16x (512 MiB -> 32
// MiB) vs one-row-per-wave; the 4-row loop gives 4 independent x-load
// streams for the scheduler to pipeline.
// ---------------------------------------------------------------------------
__global__ __launch_bounds__(256) void row_dots_kernel(
    const float* __restrict__ x,
    const float* __restrict__ v_h, const float* __restrict__ v_m,
    const float* __restrict__ Cc,
    float* __restrict__ sH, float* __restrict__ sM) {
    __shared__ float4 lvh[DD / 4];   // 4 KB
    __shared__ float4 lvm[DD / 4];   // 4 KB
    int t = threadIdx.x;
    lvh[t] = ((const float4*)v_h)[t];
    lvm[t] = ((const float4*)v_m)[t];
    __syncthreads();

    int wave = t >> 6, lane = t & 63;
    int row0 = blockIdx.x * 16 + wave * 4;           // 4 rows per wave
    float C = *Cc;

    #pragma unroll
    for (int r = 0; r < 4; ++r) {
        int row = row0 + r;
        const float4* xr = (const float4*)(x + (size_t)row * DD);
        float ah = 0.f, am = 0.f;
        #pragma unroll
        for (int k = 0; k < 4; ++k) {
            int idx = lane + 64 * k;
            float4 xv = xr[idx];
            float4 hv = lvh[idx];
            float4 mv = lvm[idx];
            ah += xv.x * hv.x + xv.y * hv.y + xv.z * hv.z + xv.w * hv.w;
            am += xv.x * mv.x + xv.y * mv.y + xv.z * mv.z + xv.w * mv.w;
        }
        #pragma unroll
        for (int off = 32; off > 0; off >>= 1) {
            ah += __shfl_down(ah, off, 64);
            am += __shfl_down(am, off, 64);
        }
        if (lane == 0) {
            sH[row] = ah + C;    // fold the scalar offset here
            sM[row] = am;
        }
    }
}

// ---------------------------------------------------------------------------
// Kernel C: out[b,i,j] = sH[b*N+i] + sM[b*N+j]   (C already inside sH)
// One block per (b,i): sH[bi] is a scalar broadcast, sM row (4 KB) L1/L2-hot,
// one float4 streaming store per thread.  (round-0 proven form)
// ---------------------------------------------------------------------------
__global__ __launch_bounds__(256) void scores_kernel(
    const float* __restrict__ sH, const float* __restrict__ sM,
    float4* __restrict__ out) {
    int bi = blockIdx.x;                              // b*N + i
    int j4 = threadIdx.x;                             // float4 index in row
    float h = sH[bi];
    const float4* mrow = (const float4*)(sM + (bi & ~(NN - 1)));
    float4 m = mrow[j4];
    float4 o;
    o.x = h + m.x;
    o.y = h + m.y;
    o.z = h + m.z;
    o.w = h + m.w;
    out[(size_t)bi * (NN / 4) + j4] = o;
}

extern "C" void kernel_launch(void* const* d_in, const int* in_sizes, int n_in,
                              void* d_out, int out_size, void* d_ws, size_t ws_size,
                              hipStream_t stream) {
    const float* x     = (const float*)d_in[0];
    const float* W_h   = (const float*)d_in[1];
    const float* b_h   = (const float*)d_in[2];
    const float* W_m   = (const float*)d_in[3];
    const float* b_m   = (const float*)d_in[4];
    const float* w_out = (const float*)d_in[5];
    const float* b_out = (const float*)d_in[6];
    float* out = (float*)d_out;

    float* ws  = (float*)d_ws;
    float* v_h = ws;               // 1024
    float* v_m = ws + 1024;        // 1024
    float* Cc  = ws + 2048;        // 1
    float* sH  = ws + 4096;        // B*N = 16384
    float* sM  = ws + 4096 + 16384;

    // zero the atomicAdd targets (ws is poisoned 0xAA before every call)
    (void)hipMemsetAsync(ws, 0, 2048 * sizeof(float), stream);

    prep_kernel<<<257, 256, 0, stream>>>(W_h, W_m, b_h, b_m, w_out, b_out, v_h, v_m, Cc);
    row_dots_kernel<<<BB * NN / 16, 256, 0, stream>>>(x, v_h, v_m, Cc, sH, sM);
    scores_kernel<<<BB * NN, 256, 0, stream>>>(sH, sM, (float4*)out);
}